// Round 2
// baseline (852.481 us; speedup 1.0000x reference)
//
#include <hip/hip_runtime.h>
#include <hip/hip_bf16.h>
#include <stdint.h>

// Problem constants (B=4, T=2048, D=2048, H=16, hd=128)
#define TDIM 2048
#define DDIM 2048
#define BDIM 4
#define HDIM 16
#define HD   128
#define E3   6144
#define KDIM 2048

typedef unsigned short u16;
typedef __bf16 bf16x8 __attribute__((ext_vector_type(8)));
typedef float  f32x4  __attribute__((ext_vector_type(4)));

__device__ __forceinline__ u16 f2bf(float f) {
  union { float f; uint32_t u; } x; x.f = f;
  uint32_t r = x.u + 0x7fffu + ((x.u >> 16) & 1u);   // RNE
  return (u16)(r >> 16);
}
__device__ __forceinline__ float bf2f(u16 u) {
  union { uint32_t u; float f; } x; x.u = ((uint32_t)u) << 16;
  return x.f;
}

// async global->LDS, 16B per lane. LDS dest must be wave-uniform base + lane*16.
__device__ __forceinline__ void load16(const void* g, void* l) {
  __builtin_amdgcn_global_load_lds(
      (const __attribute__((address_space(1))) void*)g,
      (__attribute__((address_space(3))) void*)l, 16, 0, 0);
}

// ---------------- fp32 -> bf16 convert ----------------
__global__ void cvt_kernel(const float* __restrict__ in, u16* __restrict__ out, int n) {
  int i = (blockIdx.x * 256 + threadIdx.x) * 4;
  if (i >= n) return;
  float4 v = *(const float4*)(in + i);
  ushort4 o;
  o.x = f2bf(v.x); o.y = f2bf(v.y); o.z = f2bf(v.z); o.w = f2bf(v.w);
  *(ushort4*)(out + i) = o;
}

// ---------------- GEMM: C[m][n] = sum_k A[m][k]*B[n][k]  (both K-contiguous) ----
// MODE 0: QKV. cols <4096 -> bf16 qk buffer [8192][4096]; cols >=4096 (V) ->
//         transposed bf16 vt buffer [b][h][d][t] (packs 4 consecutive t / lane).
// MODE 1: fp32 out [8192][2048].
template <int MODE>
__global__ __launch_bounds__(256) void gemm_bt(
    const u16* __restrict__ A, const u16* __restrict__ Bm,
    u16* __restrict__ qkOut, u16* __restrict__ vtOut, float* __restrict__ fOut) {
  __shared__ __align__(16) u16 As[128 * 32];
  __shared__ __align__(16) u16 Bs[128 * 32];
  const int tid = threadIdx.x;
  const int bn = blockIdx.x, bm = blockIdx.y;
  const int w = tid >> 6, lane = tid & 63;
  const int wr = w >> 1, wc = w & 1;          // 2x2 wave grid, 64x64 per wave
  const int lrow = lane & 15, lgrp = lane >> 4;

  f32x4 acc[4][4];
#pragma unroll
  for (int m = 0; m < 4; ++m)
#pragma unroll
    for (int n = 0; n < 4; ++n) {
      acc[m][n][0] = 0.f; acc[m][n][1] = 0.f; acc[m][n][2] = 0.f; acc[m][n][3] = 0.f;
    }

  const size_t aRow = (size_t)bm * 128;
  const size_t bRow = (size_t)bn * 128;

  for (int kt = 0; kt < KDIM / 32; ++kt) {
    const int kb = kt * 32;
#pragma unroll
    for (int is = 0; is < 2; ++is) {          // A tile 128x32 bf16 = 8KB
      int u = is * 256 + tid;
      int r = u >> 2, c = u & 3;
      load16(A + (aRow + r) * KDIM + kb + c * 8, (char*)As + (size_t)u * 16);
    }
#pragma unroll
    for (int is = 0; is < 2; ++is) {          // B tile 128x32
      int u = is * 256 + tid;
      int r = u >> 2, c = u & 3;
      load16(Bm + (bRow + r) * KDIM + kb + c * 8, (char*)Bs + (size_t)u * 16);
    }
    __syncthreads();                          // drains vmcnt, publishes LDS

    bf16x8 af[4], bfr[4];
#pragma unroll
    for (int m = 0; m < 4; ++m)
      af[m] = *(const bf16x8*)(As + (wr * 64 + m * 16 + lrow) * 32 + lgrp * 8);
#pragma unroll
    for (int n = 0; n < 4; ++n)
      bfr[n] = *(const bf16x8*)(Bs + (wc * 64 + n * 16 + lrow) * 32 + lgrp * 8);
#pragma unroll
    for (int m = 0; m < 4; ++m)
#pragma unroll
      for (int n = 0; n < 4; ++n)
        acc[m][n] = __builtin_amdgcn_mfma_f32_16x16x32_bf16(af[m], bfr[n], acc[m][n], 0, 0, 0);
    __syncthreads();                          // protect LDS before restage
  }

  const int col_base = bn * 128 + wc * 64;
  const int row_base = bm * 128 + wr * 64;
#pragma unroll
  for (int m = 0; m < 4; ++m) {
    int row0 = row_base + m * 16 + lgrp * 4;  // 4 consecutive rows per lane
#pragma unroll
    for (int n = 0; n < 4; ++n) {
      int col = col_base + n * 16 + lrow;
      if (MODE == 0) {
        if (bn < 32) {                        // q/k region (block-uniform branch)
#pragma unroll
          for (int i = 0; i < 4; ++i)
            qkOut[(size_t)(row0 + i) * 4096 + col] = f2bf(acc[m][n][i]);
        } else {                              // V region -> transposed vt[b][h][d][t]
          int e = col - 4096;
          int hh = e >> 7, d = e & 127;
          int bb = row0 >> 11, t0 = row0 & 2047;
          ushort4 pk;
          pk.x = f2bf(acc[m][n][0]); pk.y = f2bf(acc[m][n][1]);
          pk.z = f2bf(acc[m][n][2]); pk.w = f2bf(acc[m][n][3]);
          *(ushort4*)(vtOut + ((size_t)(bb * HDIM + hh) * HD + d) * TDIM + t0) = pk;
        }
      } else {
#pragma unroll
        for (int i = 0; i < 4; ++i)
          fOut[(size_t)(row0 + i) * DDIM + col] = acc[m][n][i];
      }
    }
  }
}

// ---------------- RoPE on q,k (in-place, bf16 buffer [8192][4096]) ----------------
__global__ void rope_kernel(u16* __restrict__ qkbuf,
                            const float* __restrict__ cosb, const float* __restrict__ sinb) {
  int gid = blockIdx.x * 256 + threadIdx.x;   // 4,194,304 threads total
  int d4 = gid & 15;                          // 4-wide d block, d = d4*4 in [0,64)
  int h = (gid >> 4) & 15;
  int which = (gid >> 8) & 1;                 // 0=q, 1=k
  int row = gid >> 9;                         // 0..8191 (b*2048+t)
  int t = row & 2047;
  u16* base = qkbuf + (size_t)row * 4096 + which * 2048 + h * HD + d4 * 4;
  ushort4 u1 = *(ushort4*)base;
  ushort4 u2 = *(ushort4*)(base + 64);
  float4 c = *(const float4*)(cosb + (size_t)t * 64 + d4 * 4);
  float4 s = *(const float4*)(sinb + (size_t)t * 64 + d4 * 4);
  float x1[4] = {bf2f(u1.x), bf2f(u1.y), bf2f(u1.z), bf2f(u1.w)};
  float x2[4] = {bf2f(u2.x), bf2f(u2.y), bf2f(u2.z), bf2f(u2.w)};
  float cc[4] = {c.x, c.y, c.z, c.w};
  float ss[4] = {s.x, s.y, s.z, s.w};
  ushort4 o1, o2;
  o1.x = f2bf(x1[0]*cc[0] - x2[0]*ss[0]); o2.x = f2bf(x2[0]*cc[0] + x1[0]*ss[0]);
  o1.y = f2bf(x1[1]*cc[1] - x2[1]*ss[1]); o2.y = f2bf(x2[1]*cc[1] + x1[1]*ss[1]);
  o1.z = f2bf(x1[2]*cc[2] - x2[2]*ss[2]); o2.z = f2bf(x2[2]*cc[2] + x1[2]*ss[2]);
  o1.w = f2bf(x1[3]*cc[3] - x2[3]*ss[3]); o2.w = f2bf(x2[3]*cc[3] + x1[3]*ss[3]);
  *(ushort4*)base = o1;
  *(ushort4*)(base + 64) = o2;
}

// ---------------- Flash attention (causal) ----------------
// grid: (T/64, B*H). 4 waves/block, wave w owns q-rows [q0+16w, q0+16w+16).
// K tile [64][128] and Vt tile [128][64] staged via global_load_lds with
// pre-swizzled SOURCE (blk ^= row&7) so ds_read_b128 is ~conflict-free (G4/m173).
__global__ __launch_bounds__(256) void attn_kernel(const u16* __restrict__ qkbuf,
                                                   const u16* __restrict__ vtbuf,
                                                   u16* __restrict__ ao) {
  __shared__ __align__(16) u16 Ks[64 * 128];
  __shared__ __align__(16) u16 Vs[128 * 64];
  __shared__ __align__(16) u16 Ps[4][16 * 64];
  const int tid = threadIdx.x;
  const int w = tid >> 6, lane = tid & 63;
  const int lrow = lane & 15, lgrp = lane >> 4;
  const int bh = blockIdx.y, b = bh >> 4, h = bh & 15;
  const int qt = blockIdx.x, q0 = qt * 64;

  const u16* qbase = qkbuf + (size_t)b * TDIM * 4096 + h * HD;
  const u16* kbase = qbase + 2048;
  const u16* vbase = vtbuf + (size_t)(b * HDIM + h) * HD * TDIM;

  const int qrow = q0 + w * 16 + lrow;
  bf16x8 qf[4];
#pragma unroll
  for (int kb = 0; kb < 4; ++kb)
    qf[kb] = *(const bf16x8*)(qbase + (size_t)qrow * 4096 + kb * 32 + lgrp * 8);

  f32x4 po[8];
#pragma unroll
  for (int n = 0; n < 8; ++n) { po[n][0]=0.f; po[n][1]=0.f; po[n][2]=0.f; po[n][3]=0.f; }
  float m_i[4], l_i[4];
#pragma unroll
  for (int i = 0; i < 4; ++i) { m_i[i] = -1e30f; l_i[i] = 0.f; }

  const float scale = 0.08838834764831845f;   // 1/sqrt(128)
  const int ntiles = qt + 1;
  for (int it = 0; it < ntiles; ++it) {
    const int kv0 = it * 64;
    __syncthreads();                          // prev compute done before restage
#pragma unroll
    for (int is = 0; is < 4; ++is) {          // K tile: 64 rows x 256B
      int u = is * 256 + tid;
      int r = u >> 4, blk = u & 15;
      load16(kbase + (size_t)(kv0 + r) * 4096 + ((blk ^ (r & 7)) * 8),
             (char*)Ks + (size_t)u * 16);
    }
#pragma unroll
    for (int is = 0; is < 4; ++is) {          // Vt tile: 128 rows x 128B
      int u = is * 256 + tid;
      int r = u >> 3, blk = u & 7;
      load16(vbase + (size_t)r * TDIM + kv0 + ((blk ^ (r & 7)) * 8),
             (char*)Vs + (size_t)u * 16);
    }
    __syncthreads();

    // S = Q K^T  (C-layout: S[qrow=lgrp*4+i][kcol=lrow] per 16-col chunk c)
    f32x4 sacc[4];
#pragma unroll
    for (int c = 0; c < 4; ++c) {
      sacc[c][0]=0.f; sacc[c][1]=0.f; sacc[c][2]=0.f; sacc[c][3]=0.f;
      int row = c * 16 + lrow;
      int swz = row & 7;
#pragma unroll
      for (int kb = 0; kb < 4; ++kb) {
        bf16x8 kf = *(const bf16x8*)(Ks + row * 128 + ((kb * 4 + lgrp) ^ swz) * 8);
        sacc[c] = __builtin_amdgcn_mfma_f32_16x16x32_bf16(qf[kb], kf, sacc[c], 0, 0, 0);
      }
    }

    // online softmax (row-reduce over 16 lanes of the lrow group)
    float sv[4][4];
    float mt[4] = {-1e30f, -1e30f, -1e30f, -1e30f};
#pragma unroll
    for (int c = 0; c < 4; ++c) {
      int kg = kv0 + c * 16 + lrow;
#pragma unroll
      for (int i = 0; i < 4; ++i) {
        int qg = q0 + w * 16 + lgrp * 4 + i;
        float v = sacc[c][i] * scale;
        if (kg > qg) v = -1e30f;              // causal mask
        sv[c][i] = v;
        mt[i] = fmaxf(mt[i], v);
      }
    }
#pragma unroll
    for (int msk = 1; msk < 16; msk <<= 1)
#pragma unroll
      for (int i = 0; i < 4; ++i) mt[i] = fmaxf(mt[i], __shfl_xor(mt[i], msk));
    float corr[4], mn[4];
#pragma unroll
    for (int i = 0; i < 4; ++i) {
      mn[i] = fmaxf(m_i[i], mt[i]);
      corr[i] = __expf(m_i[i] - mn[i]);
      m_i[i] = mn[i];
    }
    float ps[4] = {0.f, 0.f, 0.f, 0.f};
    float pv[4][4];
#pragma unroll
    for (int c = 0; c < 4; ++c)
#pragma unroll
      for (int i = 0; i < 4; ++i) {
        float p = __expf(sv[c][i] - mn[i]);   // masked -> exp(-huge)=0
        pv[c][i] = p;
        ps[i] += p;
      }
#pragma unroll
    for (int msk = 1; msk < 16; msk <<= 1)
#pragma unroll
      for (int i = 0; i < 4; ++i) ps[i] += __shfl_xor(ps[i], msk);
#pragma unroll
    for (int i = 0; i < 4; ++i) l_i[i] = l_i[i] * corr[i] + ps[i];
#pragma unroll
    for (int n = 0; n < 8; ++n)
#pragma unroll
      for (int i = 0; i < 4; ++i) po[n][i] *= corr[i];

    // P -> per-wave LDS (swizzled rows of 128B), then read back in A-layout
#pragma unroll
    for (int c = 0; c < 4; ++c) {
      int kcol = c * 16 + lrow;
#pragma unroll
      for (int i = 0; i < 4; ++i) {
        int prow = lgrp * 4 + i;
        Ps[w][prow * 64 + (((kcol >> 3) ^ (prow & 7)) * 8) + (kcol & 7)] = f2bf(pv[c][i]);
      }
    }
    bf16x8 pa[2];
#pragma unroll
    for (int kk = 0; kk < 2; ++kk)
      pa[kk] = *(const bf16x8*)(&Ps[w][lrow * 64 + (((kk * 4 + lgrp) ^ (lrow & 7)) * 8)]);
#pragma unroll
    for (int n = 0; n < 8; ++n) {
      int row = n * 16 + lrow;
      int swz = row & 7;
#pragma unroll
      for (int kk = 0; kk < 2; ++kk) {
        bf16x8 vf = *(const bf16x8*)(Vs + row * 64 + (((kk * 4 + lgrp) ^ swz) * 8));
        po[n] = __builtin_amdgcn_mfma_f32_16x16x32_bf16(pa[kk], vf, po[n], 0, 0, 0);
      }
    }
  }

  // epilogue: O / l -> ao [8192][2048] bf16
#pragma unroll
  for (int n = 0; n < 8; ++n)
#pragma unroll
    for (int i = 0; i < 4; ++i) {
      int qg = q0 + w * 16 + lgrp * 4 + i;
      float v = po[n][i] / l_i[i];
      ao[(size_t)(b * TDIM + qg) * DDIM + h * HD + n * 16 + lrow] = f2bf(v);
    }
}

// ---------------- launch ----------------
// Workspace layout (bytes), total 160 MB:
//   [0,            33554432)  xb   : x as bf16 [8192][2048]; REUSED as attention out
//   [33554432,     58720256)  wqb  : W_qkv bf16 [6144][2048]
//   [58720256,     67108864)  wob  : W_out bf16 [2048][2048]
//   [67108864,    134217728)  qkb  : q,k bf16 [8192][4096] (post-RoPE)
//   [134217728,   167772160)  vtb  : V^T bf16 [b][h][128][2048]
extern "C" void kernel_launch(void* const* d_in, const int* in_sizes, int n_in,
                              void* d_out, int out_size, void* d_ws, size_t ws_size,
                              hipStream_t stream) {
  const float* x    = (const float*)d_in[0];
  const float* cosb = (const float*)d_in[1];
  const float* sinb = (const float*)d_in[2];
  const float* wqkv = (const float*)d_in[3];
  const float* wout = (const float*)d_in[4];
  float* out = (float*)d_out;
  char* ws = (char*)d_ws;
  u16* xb  = (u16*)(ws);
  u16* wqb = (u16*)(ws + 33554432);
  u16* wob = (u16*)(ws + 58720256);
  u16* qkb = (u16*)(ws + 67108864);
  u16* vtb = (u16*)(ws + 134217728);

  cvt_kernel<<<16384, 256, 0, stream>>>(x, xb, 16777216);
  cvt_kernel<<<12288, 256, 0, stream>>>(wqkv, wqb, 12582912);
  cvt_kernel<<<4096, 256, 0, stream>>>(wout, wob, 4194304);
  gemm_bt<0><<<dim3(48, 64), 256, 0, stream>>>(xb, wqb, qkb, vtb, nullptr);
  rope_kernel<<<16384, 256, 0, stream>>>(qkb, cosb, sinb);
  attn_kernel<<<dim3(32, 64), 256, 0, stream>>>(qkb, vtb, xb);
  gemm_bt<1><<<dim3(16, 64), 256, 0, stream>>>(xb, wob, nullptr, nullptr, out);
}

// Round 4
// 734.022 us; speedup vs baseline: 1.1614x; 1.1614x over previous
//
#include <hip/hip_runtime.h>
#include <hip/hip_bf16.h>
#include <stdint.h>

// Problem constants (B=4, T=2048, D=2048, H=16, hd=128)
#define TDIM 2048
#define DDIM 2048
#define BDIM 4
#define HDIM 16
#define HD   128
#define E3   6144
#define KDIM 2048

typedef unsigned short u16;
typedef __bf16 bf16x8 __attribute__((ext_vector_type(8)));
typedef float  f32x4  __attribute__((ext_vector_type(4)));

__device__ __forceinline__ u16 f2bf(float f) {
  union { float f; uint32_t u; } x; x.f = f;
  uint32_t r = x.u + 0x7fffu + ((x.u >> 16) & 1u);   // RNE
  return (u16)(r >> 16);
}
__device__ __forceinline__ float bf2f(u16 u) {
  union { uint32_t u; float f; } x; x.u = ((uint32_t)u) << 16;
  return x.f;
}

// async global->LDS, 16B per lane. LDS dest must be wave-uniform base + lane*16.
__device__ __forceinline__ void load16(const void* g, void* l) {
  __builtin_amdgcn_global_load_lds(
      (const __attribute__((address_space(1))) void*)g,
      (__attribute__((address_space(3))) void*)l, 16, 0, 0);
}

// ---------------- fp32 -> bf16 convert ----------------
__global__ void cvt_kernel(const float* __restrict__ in, u16* __restrict__ out, int n) {
  int i = (blockIdx.x * 256 + threadIdx.x) * 4;
  if (i >= n) return;
  float4 v = *(const float4*)(in + i);
  ushort4 o;
  o.x = f2bf(v.x); o.y = f2bf(v.y); o.z = f2bf(v.z); o.w = f2bf(v.w);
  *(ushort4*)(out + i) = o;
}

// ---------------- GEMM: C[m][n] = sum_k A[m][k]*B[n][k]  (both K-contiguous) ----
// MODE 0: QKV. cols <4096 -> bf16 qk buffer [8192][4096]; cols >=4096 (V) ->
//         transposed bf16 vt buffer [b][h][d][t] (packs 4 consecutive t / lane).
// MODE 1: fp32 out [8192][2048].
template <int MODE>
__global__ __launch_bounds__(256) void gemm_bt(
    const u16* __restrict__ A, const u16* __restrict__ Bm,
    u16* __restrict__ qkOut, u16* __restrict__ vtOut, float* __restrict__ fOut) {
  __shared__ __align__(16) u16 As[128 * 32];
  __shared__ __align__(16) u16 Bs[128 * 32];
  const int tid = threadIdx.x;
  const int bn = blockIdx.x, bm = blockIdx.y;
  const int w = tid >> 6, lane = tid & 63;
  const int wr = w >> 1, wc = w & 1;          // 2x2 wave grid, 64x64 per wave
  const int lrow = lane & 15, lgrp = lane >> 4;

  f32x4 acc[4][4];
#pragma unroll
  for (int m = 0; m < 4; ++m)
#pragma unroll
    for (int n = 0; n < 4; ++n) {
      acc[m][n][0] = 0.f; acc[m][n][1] = 0.f; acc[m][n][2] = 0.f; acc[m][n][3] = 0.f;
    }

  const size_t aRow = (size_t)bm * 128;
  const size_t bRow = (size_t)bn * 128;

  for (int kt = 0; kt < KDIM / 32; ++kt) {
    const int kb = kt * 32;
#pragma unroll
    for (int is = 0; is < 2; ++is) {          // A tile 128x32 bf16 = 8KB
      int u = is * 256 + tid;
      int r = u >> 2, c = u & 3;
      load16(A + (aRow + r) * KDIM + kb + c * 8, (char*)As + (size_t)u * 16);
    }
#pragma unroll
    for (int is = 0; is < 2; ++is) {          // B tile 128x32
      int u = is * 256 + tid;
      int r = u >> 2, c = u & 3;
      load16(Bm + (bRow + r) * KDIM + kb + c * 8, (char*)Bs + (size_t)u * 16);
    }
    __syncthreads();                          // drains vmcnt, publishes LDS

    bf16x8 af[4], bfr[4];
#pragma unroll
    for (int m = 0; m < 4; ++m)
      af[m] = *(const bf16x8*)(As + (wr * 64 + m * 16 + lrow) * 32 + lgrp * 8);
#pragma unroll
    for (int n = 0; n < 4; ++n)
      bfr[n] = *(const bf16x8*)(Bs + (wc * 64 + n * 16 + lrow) * 32 + lgrp * 8);
#pragma unroll
    for (int m = 0; m < 4; ++m)
#pragma unroll
      for (int n = 0; n < 4; ++n)
        acc[m][n] = __builtin_amdgcn_mfma_f32_16x16x32_bf16(af[m], bfr[n], acc[m][n], 0, 0, 0);
    __syncthreads();                          // protect LDS before restage
  }

  const int col_base = bn * 128 + wc * 64;
  const int row_base = bm * 128 + wr * 64;
#pragma unroll
  for (int m = 0; m < 4; ++m) {
    int row0 = row_base + m * 16 + lgrp * 4;  // 4 consecutive rows per lane
#pragma unroll
    for (int n = 0; n < 4; ++n) {
      int col = col_base + n * 16 + lrow;
      if (MODE == 0) {
        if (bn < 32) {                        // q/k region (block-uniform branch)
#pragma unroll
          for (int i = 0; i < 4; ++i)
            qkOut[(size_t)(row0 + i) * 4096 + col] = f2bf(acc[m][n][i]);
        } else {                              // V region -> transposed vt[b][h][d][t]
          int e = col - 4096;
          int hh = e >> 7, d = e & 127;
          int bb = row0 >> 11, t0 = row0 & 2047;
          ushort4 pk;
          pk.x = f2bf(acc[m][n][0]); pk.y = f2bf(acc[m][n][1]);
          pk.z = f2bf(acc[m][n][2]); pk.w = f2bf(acc[m][n][3]);
          *(ushort4*)(vtOut + ((size_t)(bb * HDIM + hh) * HD + d) * TDIM + t0) = pk;
        }
      } else {
#pragma unroll
        for (int i = 0; i < 4; ++i)
          fOut[(size_t)(row0 + i) * DDIM + col] = acc[m][n][i];
      }
    }
  }
}

// ---------------- RoPE on q,k (in-place, bf16 buffer [8192][4096]) ----------------
__global__ void rope_kernel(u16* __restrict__ qkbuf,
                            const float* __restrict__ cosb, const float* __restrict__ sinb) {
  int gid = blockIdx.x * 256 + threadIdx.x;   // 4,194,304 threads total
  int d4 = gid & 15;                          // 4-wide d block, d = d4*4 in [0,64)
  int h = (gid >> 4) & 15;
  int which = (gid >> 8) & 1;                 // 0=q, 1=k
  int row = gid >> 9;                         // 0..8191 (b*2048+t)
  int t = row & 2047;
  u16* base = qkbuf + (size_t)row * 4096 + which * 2048 + h * HD + d4 * 4;
  ushort4 u1 = *(ushort4*)base;
  ushort4 u2 = *(ushort4*)(base + 64);
  float4 c = *(const float4*)(cosb + (size_t)t * 64 + d4 * 4);
  float4 s = *(const float4*)(sinb + (size_t)t * 64 + d4 * 4);
  float x1[4] = {bf2f(u1.x), bf2f(u1.y), bf2f(u1.z), bf2f(u1.w)};
  float x2[4] = {bf2f(u2.x), bf2f(u2.y), bf2f(u2.z), bf2f(u2.w)};
  float cc[4] = {c.x, c.y, c.z, c.w};
  float ss[4] = {s.x, s.y, s.z, s.w};
  ushort4 o1, o2;
  o1.x = f2bf(x1[0]*cc[0] - x2[0]*ss[0]); o2.x = f2bf(x2[0]*cc[0] + x1[0]*ss[0]);
  o1.y = f2bf(x1[1]*cc[1] - x2[1]*ss[1]); o2.y = f2bf(x2[1]*cc[1] + x1[1]*ss[1]);
  o1.z = f2bf(x1[2]*cc[2] - x2[2]*ss[2]); o2.z = f2bf(x2[2]*cc[2] + x1[2]*ss[2]);
  o1.w = f2bf(x1[3]*cc[3] - x2[3]*ss[3]); o2.w = f2bf(x2[3]*cc[3] + x1[3]*ss[3]);
  *(ushort4*)base = o1;
  *(ushort4*)(base + 64) = o2;
}

// ---------------- Flash attention (causal) ----------------
// grid: (T/128, B*H) with q-tile PAIRING for load balance: block x handles
// q-tiles {x, 31-x} -> every block does exactly 33 KV-tiles (was 1..32, the
// 1:32 imbalance caused the 11.5% occupancy straggler tail in round 2).
// 1024 blocks = 256 CU x 4 blocks/CU (40KB LDS each) -> uniform residency.
// K tile [64][128] and Vt tile [128][64] staged via global_load_lds with
// pre-swizzled SOURCE (blk ^= row&7) so ds_read_b128 is ~conflict-free.
// Softmax in log2 domain (native v_exp_f32) + T13 defer-max (THR=11 log2).
__global__ __launch_bounds__(256) void attn_kernel(const u16* __restrict__ qkbuf,
                                                   const u16* __restrict__ vtbuf,
                                                   u16* __restrict__ ao) {
  __shared__ __align__(16) u16 Ks[64 * 128];
  __shared__ __align__(16) u16 Vs[128 * 64];
  __shared__ __align__(16) u16 Ps[4][16 * 64];
  const int tid = threadIdx.x;
  const int w = tid >> 6, lane = tid & 63;
  const int lrow = lane & 15, lgrp = lane >> 4;
  const int bh = blockIdx.y, b = bh >> 4, h = bh & 15;

  const u16* qbase = qkbuf + (size_t)b * TDIM * 4096 + h * HD;
  const u16* kbase = qbase + 2048;
  const u16* vbase = vtbuf + (size_t)(b * HDIM + h) * HD * TDIM;

  // score scale folded with log2(e): softmax runs in log2 domain
  const float scale2 = 0.08838834764831845f * 1.4426950408889634f;

  for (int pass = 0; pass < 2; ++pass) {
    const int qt = pass == 0 ? (int)blockIdx.x : (31 - (int)blockIdx.x);
    const int q0 = qt * 64;

    const int qrow = q0 + w * 16 + lrow;
    bf16x8 qf[4];
#pragma unroll
    for (int kb = 0; kb < 4; ++kb)
      qf[kb] = *(const bf16x8*)(qbase + (size_t)qrow * 4096 + kb * 32 + lgrp * 8);

    f32x4 po[8];
#pragma unroll
    for (int n = 0; n < 8; ++n) { po[n][0]=0.f; po[n][1]=0.f; po[n][2]=0.f; po[n][3]=0.f; }
    float m_i[4], l_i[4];
#pragma unroll
    for (int i = 0; i < 4; ++i) { m_i[i] = -1e30f; l_i[i] = 0.f; }

    const int ntiles = qt + 1;
    for (int it = 0; it < ntiles; ++it) {
      const int kv0 = it * 64;
      __syncthreads();                        // prev compute done before restage
#pragma unroll
      for (int is = 0; is < 4; ++is) {        // K tile: 64 rows x 256B
        int u = is * 256 + tid;
        int r = u >> 4, blk = u & 15;
        load16(kbase + (size_t)(kv0 + r) * 4096 + ((blk ^ (r & 7)) * 8),
               (char*)Ks + (size_t)u * 16);
      }
#pragma unroll
      for (int is = 0; is < 4; ++is) {        // Vt tile: 128 rows x 128B
        int u = is * 256 + tid;
        int r = u >> 3, blk = u & 7;
        load16(vbase + (size_t)r * TDIM + kv0 + ((blk ^ (r & 7)) * 8),
               (char*)Vs + (size_t)u * 16);
      }
      __syncthreads();

      // S = Q K^T  (C-layout: S[qrow=lgrp*4+i][kcol=lrow] per 16-col chunk c)
      f32x4 sacc[4];
#pragma unroll
      for (int c = 0; c < 4; ++c) {
        sacc[c][0]=0.f; sacc[c][1]=0.f; sacc[c][2]=0.f; sacc[c][3]=0.f;
        int row = c * 16 + lrow;
        int swz = row & 7;
#pragma unroll
        for (int kb = 0; kb < 4; ++kb) {
          bf16x8 kf = *(const bf16x8*)(Ks + row * 128 + ((kb * 4 + lgrp) ^ swz) * 8);
          sacc[c] = __builtin_amdgcn_mfma_f32_16x16x32_bf16(qf[kb], kf, sacc[c], 0, 0, 0);
        }
      }

      // online softmax in log2 domain (row-reduce over the 16 lrow lanes)
      float sv[4][4];
      float mt[4] = {-1e30f, -1e30f, -1e30f, -1e30f};
#pragma unroll
      for (int c = 0; c < 4; ++c) {
        int kg = kv0 + c * 16 + lrow;
#pragma unroll
        for (int i = 0; i < 4; ++i) {
          int qg = q0 + w * 16 + lgrp * 4 + i;
          float v = sacc[c][i] * scale2;
          if (kg > qg) v = -1e30f;            // causal mask
          sv[c][i] = v;
          mt[i] = fmaxf(mt[i], v);
        }
      }
#pragma unroll
      for (int msk = 1; msk < 16; msk <<= 1)
#pragma unroll
        for (int i = 0; i < 4; ++i) mt[i] = fmaxf(mt[i], __shfl_xor(mt[i], msk));

      // T13 defer-max: only rescale when some row's max grew past THR
      bool grow = (mt[0] > m_i[0] + 11.f) || (mt[1] > m_i[1] + 11.f) ||
                  (mt[2] > m_i[2] + 11.f) || (mt[3] > m_i[3] + 11.f);
      if (__any(grow)) {
#pragma unroll
        for (int i = 0; i < 4; ++i) {
          float mn = fmaxf(m_i[i], mt[i]);
          float corr = exp2f(m_i[i] - mn);
          m_i[i] = mn;
          l_i[i] *= corr;
#pragma unroll
          for (int n = 0; n < 8; ++n) po[n][i] *= corr;
        }
      }

      float ps[4] = {0.f, 0.f, 0.f, 0.f};
      float pv[4][4];
#pragma unroll
      for (int c = 0; c < 4; ++c)
#pragma unroll
        for (int i = 0; i < 4; ++i) {
          float p = exp2f(sv[c][i] - m_i[i]); // masked -> exp2(-huge)=0
          pv[c][i] = p;
          ps[i] += p;
        }
#pragma unroll
      for (int msk = 1; msk < 16; msk <<= 1)
#pragma unroll
        for (int i = 0; i < 4; ++i) ps[i] += __shfl_xor(ps[i], msk);
#pragma unroll
      for (int i = 0; i < 4; ++i) l_i[i] += ps[i];

      // P -> per-wave LDS (swizzled rows of 128B), then read back in A-layout
#pragma unroll
      for (int c = 0; c < 4; ++c) {
        int kcol = c * 16 + lrow;
#pragma unroll
        for (int i = 0; i < 4; ++i) {
          int prow = lgrp * 4 + i;
          Ps[w][prow * 64 + (((kcol >> 3) ^ (prow & 7)) * 8) + (kcol & 7)] = f2bf(pv[c][i]);
        }
      }
      bf16x8 pa[2];
#pragma unroll
      for (int kk = 0; kk < 2; ++kk)
        pa[kk] = *(const bf16x8*)(&Ps[w][lrow * 64 + (((kk * 4 + lgrp) ^ (lrow & 7)) * 8)]);
#pragma unroll
      for (int n = 0; n < 8; ++n) {
        int row = n * 16 + lrow;
        int swz = row & 7;
#pragma unroll
        for (int kk = 0; kk < 2; ++kk) {
          bf16x8 vf = *(const bf16x8*)(Vs + row * 64 + (((kk * 4 + lgrp) ^ swz) * 8));
          po[n] = __builtin_amdgcn_mfma_f32_16x16x32_bf16(pa[kk], vf, po[n], 0, 0, 0);
        }
      }
    }

    // epilogue: O / l -> ao [8192][2048] bf16
#pragma unroll
    for (int n = 0; n < 8; ++n)
#pragma unroll
      for (int i = 0; i < 4; ++i) {
        int qg = q0 + w * 16 + lgrp * 4 + i;
        float v = po[n][i] / l_i[i];
        ao[(size_t)(b * TDIM + qg) * DDIM + h * HD + n * 16 + lrow] = f2bf(v);
      }
  }
}

// ---------------- launch ----------------
// Workspace layout (bytes), total 160 MB:
//   [0,            33554432)  xb   : x as bf16 [8192][2048]; REUSED as attention out
//   [33554432,     58720256)  wqb  : W_qkv bf16 [6144][2048]
//   [58720256,     67108864)  wob  : W_out bf16 [2048][2048]
//   [67108864,    134217728)  qkb  : q,k bf16 [8192][4096] (post-RoPE)
//   [134217728,   167772160)  vtb  : V^T bf16 [b][h][128][2048]
extern "C" void kernel_launch(void* const* d_in, const int* in_sizes, int n_in,
                              void* d_out, int out_size, void* d_ws, size_t ws_size,
                              hipStream_t stream) {
  const float* x    = (const float*)d_in[0];
  const float* cosb = (const float*)d_in[1];
  const float* sinb = (const float*)d_in[2];
  const float* wqkv = (const float*)d_in[3];
  const float* wout = (const float*)d_in[4];
  float* out = (float*)d_out;
  char* ws = (char*)d_ws;
  u16* xb  = (u16*)(ws);
  u16* wqb = (u16*)(ws + 33554432);
  u16* wob = (u16*)(ws + 58720256);
  u16* qkb = (u16*)(ws + 67108864);
  u16* vtb = (u16*)(ws + 134217728);

  cvt_kernel<<<16384, 256, 0, stream>>>(x, xb, 16777216);
  cvt_kernel<<<12288, 256, 0, stream>>>(wqkv, wqb, 12582912);
  cvt_kernel<<<4096, 256, 0, stream>>>(wob ? wout : wout, wob, 4194304);
  gemm_bt<0><<<dim3(48, 64), 256, 0, stream>>>(xb, wqb, qkb, vtb, nullptr);
  rope_kernel<<<16384, 256, 0, stream>>>(qkb, cosb, sinb);
  attn_kernel<<<dim3(16, 64), 256, 0, stream>>>(qkb, vtb, xb);
  gemm_bt<1><<<dim3(16, 64), 256, 0, stream>>>(xb, wob, nullptr, nullptr, out);
}

// Round 5
// 664.274 us; speedup vs baseline: 1.2833x; 1.1050x over previous
//
#include <hip/hip_runtime.h>
#include <hip/hip_bf16.h>
#include <stdint.h>

// Problem constants (B=4, T=2048, D=2048, H=16, hd=128)
#define TDIM 2048
#define DDIM 2048
#define BDIM 4
#define HDIM 16
#define HD   128
#define E3   6144
#define KDIM 2048

typedef unsigned short u16;
typedef __bf16 bf16x8 __attribute__((ext_vector_type(8)));
typedef float  f32x4  __attribute__((ext_vector_type(4)));

__device__ __forceinline__ u16 f2bf(float f) {
  union { float f; uint32_t u; } x; x.f = f;
  uint32_t r = x.u + 0x7fffu + ((x.u >> 16) & 1u);   // RNE
  return (u16)(r >> 16);
}
__device__ __forceinline__ float bf2f(u16 u) {
  union { uint32_t u; float f; } x; x.u = ((uint32_t)u) << 16;
  return x.f;
}

// async global->LDS, 16B per lane. LDS dest must be wave-uniform base + lane*16.
__device__ __forceinline__ void load16(const void* g, void* l) {
  __builtin_amdgcn_global_load_lds(
      (const __attribute__((address_space(1))) void*)g,
      (__attribute__((address_space(3))) void*)l, 16, 0, 0);
}

// ---------------- fp32 -> bf16 convert ----------------
__global__ void cvt_kernel(const float* __restrict__ in, u16* __restrict__ out, int n) {
  int i = (blockIdx.x * 256 + threadIdx.x) * 4;
  if (i >= n) return;
  float4 v = *(const float4*)(in + i);
  ushort4 o;
  o.x = f2bf(v.x); o.y = f2bf(v.y); o.z = f2bf(v.z); o.w = f2bf(v.w);
  *(ushort4*)(out + i) = o;
}

// ---------------- GEMM: C[m][n] = sum_k A[m][k]*B[n][k]  (both K-contiguous) ----
// BK=64 (rows of 128B in LDS). Round-4 counters showed 2.5e7 bank conflicts
// (8-way on 64B rows at BK=32): now XOR-swizzled (pre-swizzled global source +
// swizzled ds_read, m173 both-sides pattern) -> 2-way (free). BK=64 halves the
// barrier/vmcnt-drain count (the m97 structural ~20% stall) per K.
// MODE 0: QKV. cols <4096 -> bf16 qk buffer [8192][4096]; cols >=4096 (V) ->
//         transposed bf16 vt buffer [b][h][d][t] (packs 4 consecutive t / lane).
// MODE 1: fp32 out [8192][2048].
template <int MODE>
__global__ __launch_bounds__(256) void gemm_bt(
    const u16* __restrict__ A, const u16* __restrict__ Bm,
    u16* __restrict__ qkOut, u16* __restrict__ vtOut, float* __restrict__ fOut) {
  __shared__ __align__(16) u16 As[128 * 64];  // 16 KB, swizzled rows of 128B
  __shared__ __align__(16) u16 Bs[128 * 64];  // 16 KB
  const int tid = threadIdx.x;
  const int bn = blockIdx.x, bm = blockIdx.y;
  const int w = tid >> 6, lane = tid & 63;
  const int wr = w >> 1, wc = w & 1;          // 2x2 wave grid, 64x64 per wave
  const int lrow = lane & 15, lgrp = lane >> 4;

  f32x4 acc[4][4];
#pragma unroll
  for (int m = 0; m < 4; ++m)
#pragma unroll
    for (int n = 0; n < 4; ++n) {
      acc[m][n][0] = 0.f; acc[m][n][1] = 0.f; acc[m][n][2] = 0.f; acc[m][n][3] = 0.f;
    }

  const size_t aRow = (size_t)bm * 128;
  const size_t bRow = (size_t)bn * 128;

  for (int kt = 0; kt < KDIM / 64; ++kt) {    // 32 iters
    const int kb = kt * 64;
#pragma unroll
    for (int is = 0; is < 4; ++is) {          // A tile 128x64 bf16 = 16KB
      int u = is * 256 + tid;
      int r = u >> 3, blk = u & 7;            // pre-swizzled SOURCE col
      load16(A + (aRow + r) * KDIM + kb + ((blk ^ (r & 7)) * 8),
             (char*)As + (size_t)u * 16);
    }
#pragma unroll
    for (int is = 0; is < 4; ++is) {          // B tile 128x64
      int u = is * 256 + tid;
      int r = u >> 3, blk = u & 7;
      load16(Bm + (bRow + r) * KDIM + kb + ((blk ^ (r & 7)) * 8),
             (char*)Bs + (size_t)u * 16);
    }
    __syncthreads();                          // drains vmcnt, publishes LDS

#pragma unroll
    for (int kk = 0; kk < 2; ++kk) {
      bf16x8 af[4], bfr[4];
#pragma unroll
      for (int m = 0; m < 4; ++m) {
        int row = wr * 64 + m * 16 + lrow;
        af[m] = *(const bf16x8*)(As + row * 64 + (((kk * 4 + lgrp) ^ (row & 7)) * 8));
      }
#pragma unroll
      for (int n = 0; n < 4; ++n) {
        int row = wc * 64 + n * 16 + lrow;
        bfr[n] = *(const bf16x8*)(Bs + row * 64 + (((kk * 4 + lgrp) ^ (row & 7)) * 8));
      }
#pragma unroll
      for (int m = 0; m < 4; ++m)
#pragma unroll
        for (int n = 0; n < 4; ++n)
          acc[m][n] = __builtin_amdgcn_mfma_f32_16x16x32_bf16(af[m], bfr[n], acc[m][n], 0, 0, 0);
    }
    __syncthreads();                          // protect LDS before restage
  }

  const int col_base = bn * 128 + wc * 64;
  const int row_base = bm * 128 + wr * 64;
#pragma unroll
  for (int m = 0; m < 4; ++m) {
    int row0 = row_base + m * 16 + lgrp * 4;  // 4 consecutive rows per lane
#pragma unroll
    for (int n = 0; n < 4; ++n) {
      int col = col_base + n * 16 + lrow;
      if (MODE == 0) {
        if (bn < 32) {                        // q/k region (block-uniform branch)
#pragma unroll
          for (int i = 0; i < 4; ++i)
            qkOut[(size_t)(row0 + i) * 4096 + col] = f2bf(acc[m][n][i]);
        } else {                              // V region -> transposed vt[b][h][d][t]
          int e = col - 4096;
          int hh = e >> 7, d = e & 127;
          int bb = row0 >> 11, t0 = row0 & 2047;
          ushort4 pk;
          pk.x = f2bf(acc[m][n][0]); pk.y = f2bf(acc[m][n][1]);
          pk.z = f2bf(acc[m][n][2]); pk.w = f2bf(acc[m][n][3]);
          *(ushort4*)(vtOut + ((size_t)(bb * HDIM + hh) * HD + d) * TDIM + t0) = pk;
        }
      } else {
#pragma unroll
        for (int i = 0; i < 4; ++i)
          fOut[(size_t)(row0 + i) * DDIM + col] = acc[m][n][i];
      }
    }
  }
}

// ---------------- RoPE on q,k (in-place, bf16 buffer [8192][4096]) ----------------
__global__ void rope_kernel(u16* __restrict__ qkbuf,
                            const float* __restrict__ cosb, const float* __restrict__ sinb) {
  int gid = blockIdx.x * 256 + threadIdx.x;   // 4,194,304 threads total
  int d4 = gid & 15;                          // 4-wide d block, d = d4*4 in [0,64)
  int h = (gid >> 4) & 15;
  int which = (gid >> 8) & 1;                 // 0=q, 1=k
  int row = gid >> 9;                         // 0..8191 (b*2048+t)
  int t = row & 2047;
  u16* base = qkbuf + (size_t)row * 4096 + which * 2048 + h * HD + d4 * 4;
  ushort4 u1 = *(ushort4*)base;
  ushort4 u2 = *(ushort4*)(base + 64);
  float4 c = *(const float4*)(cosb + (size_t)t * 64 + d4 * 4);
  float4 s = *(const float4*)(sinb + (size_t)t * 64 + d4 * 4);
  float x1[4] = {bf2f(u1.x), bf2f(u1.y), bf2f(u1.z), bf2f(u1.w)};
  float x2[4] = {bf2f(u2.x), bf2f(u2.y), bf2f(u2.z), bf2f(u2.w)};
  float cc[4] = {c.x, c.y, c.z, c.w};
  float ss[4] = {s.x, s.y, s.z, s.w};
  ushort4 o1, o2;
  o1.x = f2bf(x1[0]*cc[0] - x2[0]*ss[0]); o2.x = f2bf(x2[0]*cc[0] + x1[0]*ss[0]);
  o1.y = f2bf(x1[1]*cc[1] - x2[1]*ss[1]); o2.y = f2bf(x2[1]*cc[1] + x1[1]*ss[1]);
  o1.z = f2bf(x1[2]*cc[2] - x2[2]*ss[2]); o2.z = f2bf(x2[2]*cc[2] + x1[2]*ss[2]);
  o1.w = f2bf(x1[3]*cc[3] - x2[3]*ss[3]); o2.w = f2bf(x2[3]*cc[3] + x1[3]*ss[3]);
  *(ushort4*)base = o1;
  *(ushort4*)(base + 64) = o2;
}

// ---------------- Flash attention (causal) ----------------
// grid: (T/128, B*H), q-tile pairing {x, 31-x}: uniform 33 KV-tiles/block,
// 1024 blocks = 4/CU (40KB LDS). K/Vt staged via global_load_lds with
// pre-swizzled SOURCE; softmax in log2 domain; T13 defer-max (THR=11 log2).
// Round-5: l-sum kept LANE-PARTIAL (reduced once in epilogue; corr is
// row-uniform so scaling partials is exact); causal mask only on it==qt.
__global__ __launch_bounds__(256) void attn_kernel(const u16* __restrict__ qkbuf,
                                                   const u16* __restrict__ vtbuf,
                                                   u16* __restrict__ ao) {
  __shared__ __align__(16) u16 Ks[64 * 128];
  __shared__ __align__(16) u16 Vs[128 * 64];
  __shared__ __align__(16) u16 Ps[4][16 * 64];
  const int tid = threadIdx.x;
  const int w = tid >> 6, lane = tid & 63;
  const int lrow = lane & 15, lgrp = lane >> 4;
  const int bh = blockIdx.y, b = bh >> 4, h = bh & 15;

  const u16* qbase = qkbuf + (size_t)b * TDIM * 4096 + h * HD;
  const u16* kbase = qbase + 2048;
  const u16* vbase = vtbuf + (size_t)(b * HDIM + h) * HD * TDIM;

  // score scale folded with log2(e): softmax runs in log2 domain
  const float scale2 = 0.08838834764831845f * 1.4426950408889634f;

  for (int pass = 0; pass < 2; ++pass) {
    const int qt = pass == 0 ? (int)blockIdx.x : (31 - (int)blockIdx.x);
    const int q0 = qt * 64;

    const int qrow = q0 + w * 16 + lrow;
    bf16x8 qf[4];
#pragma unroll
    for (int kb = 0; kb < 4; ++kb)
      qf[kb] = *(const bf16x8*)(qbase + (size_t)qrow * 4096 + kb * 32 + lgrp * 8);

    f32x4 po[8];
#pragma unroll
    for (int n = 0; n < 8; ++n) { po[n][0]=0.f; po[n][1]=0.f; po[n][2]=0.f; po[n][3]=0.f; }
    float m_i[4], l_i[4];                     // l_i is LANE-PARTIAL (16 lanes/row)
#pragma unroll
    for (int i = 0; i < 4; ++i) { m_i[i] = -1e30f; l_i[i] = 0.f; }

    const int ntiles = qt + 1;
    for (int it = 0; it < ntiles; ++it) {
      const int kv0 = it * 64;
      __syncthreads();                        // prev compute done before restage
#pragma unroll
      for (int is = 0; is < 4; ++is) {        // K tile: 64 rows x 256B
        int u = is * 256 + tid;
        int r = u >> 4, blk = u & 15;
        load16(kbase + (size_t)(kv0 + r) * 4096 + ((blk ^ (r & 7)) * 8),
               (char*)Ks + (size_t)u * 16);
      }
#pragma unroll
      for (int is = 0; is < 4; ++is) {        // Vt tile: 128 rows x 128B
        int u = is * 256 + tid;
        int r = u >> 3, blk = u & 7;
        load16(vbase + (size_t)r * TDIM + kv0 + ((blk ^ (r & 7)) * 8),
               (char*)Vs + (size_t)u * 16);
      }
      __syncthreads();

      // S = Q K^T  (C-layout: S[qrow=lgrp*4+i][kcol=lrow] per 16-col chunk c)
      f32x4 sacc[4];
#pragma unroll
      for (int c = 0; c < 4; ++c) {
        sacc[c][0]=0.f; sacc[c][1]=0.f; sacc[c][2]=0.f; sacc[c][3]=0.f;
        int row = c * 16 + lrow;
        int swz = row & 7;
#pragma unroll
        for (int kb = 0; kb < 4; ++kb) {
          bf16x8 kf = *(const bf16x8*)(Ks + row * 128 + ((kb * 4 + lgrp) ^ swz) * 8);
          sacc[c] = __builtin_amdgcn_mfma_f32_16x16x32_bf16(qf[kb], kf, sacc[c], 0, 0, 0);
        }
      }

      // online softmax in log2 domain (row-reduce over the 16 lrow lanes)
      float sv[4][4];
      float mt[4] = {-1e30f, -1e30f, -1e30f, -1e30f};
      if (it == qt) {                         // diagonal tile: causal mask needed
#pragma unroll
        for (int c = 0; c < 4; ++c) {
          int kg = kv0 + c * 16 + lrow;
#pragma unroll
          for (int i = 0; i < 4; ++i) {
            int qg = q0 + w * 16 + lgrp * 4 + i;
            float v = sacc[c][i] * scale2;
            if (kg > qg) v = -1e30f;
            sv[c][i] = v;
            mt[i] = fmaxf(mt[i], v);
          }
        }
      } else {                                // interior tile: mask-free
#pragma unroll
        for (int c = 0; c < 4; ++c)
#pragma unroll
          for (int i = 0; i < 4; ++i) {
            float v = sacc[c][i] * scale2;
            sv[c][i] = v;
            mt[i] = fmaxf(mt[i], v);
          }
      }
#pragma unroll
      for (int msk = 1; msk < 16; msk <<= 1)
#pragma unroll
        for (int i = 0; i < 4; ++i) mt[i] = fmaxf(mt[i], __shfl_xor(mt[i], msk));

      // T13 defer-max: only rescale when some row's max grew past THR
      bool grow = (mt[0] > m_i[0] + 11.f) || (mt[1] > m_i[1] + 11.f) ||
                  (mt[2] > m_i[2] + 11.f) || (mt[3] > m_i[3] + 11.f);
      if (__any(grow)) {
#pragma unroll
        for (int i = 0; i < 4; ++i) {
          float mn = fmaxf(m_i[i], mt[i]);
          float corr = exp2f(m_i[i] - mn);    // row-uniform: partials scale exactly
          m_i[i] = mn;
          l_i[i] *= corr;
#pragma unroll
          for (int n = 0; n < 8; ++n) po[n][i] *= corr;
        }
      }

      float pv[4][4];
#pragma unroll
      for (int c = 0; c < 4; ++c)
#pragma unroll
        for (int i = 0; i < 4; ++i) {
          float p = exp2f(sv[c][i] - m_i[i]); // masked -> exp2(-huge)=0
          pv[c][i] = p;
          l_i[i] += p;                        // lane-partial; reduced in epilogue
        }

      // P -> per-wave LDS (swizzled rows of 128B), then read back in A-layout
#pragma unroll
      for (int c = 0; c < 4; ++c) {
        int kcol = c * 16 + lrow;
#pragma unroll
        for (int i = 0; i < 4; ++i) {
          int prow = lgrp * 4 + i;
          Ps[w][prow * 64 + (((kcol >> 3) ^ (prow & 7)) * 8) + (kcol & 7)] = f2bf(pv[c][i]);
        }
      }
      bf16x8 pa[2];
#pragma unroll
      for (int kk = 0; kk < 2; ++kk)
        pa[kk] = *(const bf16x8*)(&Ps[w][lrow * 64 + (((kk * 4 + lgrp) ^ (lrow & 7)) * 8)]);
#pragma unroll
      for (int n = 0; n < 8; ++n) {
        int row = n * 16 + lrow;
        int swz = row & 7;
#pragma unroll
        for (int kk = 0; kk < 2; ++kk) {
          bf16x8 vf = *(const bf16x8*)(Vs + row * 64 + (((kk * 4 + lgrp) ^ swz) * 8));
          po[n] = __builtin_amdgcn_mfma_f32_16x16x32_bf16(pa[kk], vf, po[n], 0, 0, 0);
        }
      }
    }

    // epilogue: reduce lane-partial l (over the 16 lrow lanes), then O/l -> ao
#pragma unroll
    for (int msk = 1; msk < 16; msk <<= 1)
#pragma unroll
      for (int i = 0; i < 4; ++i) l_i[i] += __shfl_xor(l_i[i], msk);
#pragma unroll
    for (int n = 0; n < 8; ++n)
#pragma unroll
      for (int i = 0; i < 4; ++i) {
        int qg = q0 + w * 16 + lgrp * 4 + i;
        float v = po[n][i] / l_i[i];
        ao[(size_t)(b * TDIM + qg) * DDIM + h * HD + n * 16 + lrow] = f2bf(v);
      }
  }
}

// ---------------- launch ----------------
// Workspace layout (bytes), total 160 MB:
//   [0,            33554432)  xb   : x as bf16 [8192][2048]; REUSED as attention out
//   [33554432,     58720256)  wqb  : W_qkv bf16 [6144][2048]
//   [58720256,     67108864)  wob  : W_out bf16 [2048][2048]
//   [67108864,    134217728)  qkb  : q,k bf16 [8192][4096] (post-RoPE)
//   [134217728,   167772160)  vtb  : V^T bf16 [b][h][128][2048]
extern "C" void kernel_launch(void* const* d_in, const int* in_sizes, int n_in,
                              void* d_out, int out_size, void* d_ws, size_t ws_size,
                              hipStream_t stream) {
  const float* x    = (const float*)d_in[0];
  const float* cosb = (const float*)d_in[1];
  const float* sinb = (const float*)d_in[2];
  const float* wqkv = (const float*)d_in[3];
  const float* wout = (const float*)d_in[4];
  float* out = (float*)d_out;
  char* ws = (char*)d_ws;
  u16* xb  = (u16*)(ws);
  u16* wqb = (u16*)(ws + 33554432);
  u16* wob = (u16*)(ws + 58720256);
  u16* qkb = (u16*)(ws + 67108864);
  u16* vtb = (u16*)(ws + 134217728);

  cvt_kernel<<<16384, 256, 0, stream>>>(x, xb, 16777216);
  cvt_kernel<<<12288, 256, 0, stream>>>(wqkv, wqb, 12582912);
  cvt_kernel<<<4096, 256, 0, stream>>>(wout, wob, 4194304);
  gemm_bt<0><<<dim3(48, 64), 256, 0, stream>>>(xb, wqb, qkb, vtb, nullptr);
  rope_kernel<<<16384, 256, 0, stream>>>(qkb, cosb, sinb);
  attn_kernel<<<dim3(16, 64), 256, 0, stream>>>(qkb, vtb, xb);
  gemm_bt<1><<<dim3(16, 64), 256, 0, stream>>>(xb, wob, nullptr, nullptr, out);
}